// Round 3
// baseline (190.123 us; speedup 1.0000x reference)
//
#include <hip/hip_runtime.h>

#define BATCH  32768
#define ADIM   16
#define HDIM   256
#define DDIM   128
#define KCODES 2048
#define SA     264   // LDS row stride in u16 (256 cols + 8 pad; 528 B = 16B-aligned)

typedef unsigned short u16;
typedef short s16x8 __attribute__((ext_vector_type(8)));   // 8 x bf16 bits (guide-verified MFMA frag type)
typedef float f32x4 __attribute__((ext_vector_type(4)));

__device__ __forceinline__ float b2f(u16 u) {
    return __uint_as_float(((unsigned)u) << 16);
}
__device__ __forceinline__ u16 f2b(float f) {
    unsigned u = __float_as_uint(f);
    u += 0x7fffu + ((u >> 16) & 1u);   // RNE
    return (u16)(u >> 16);
}
__device__ __forceinline__ s16x8 ldb8(const u16* p) {
    return *reinterpret_cast<const s16x8*>(p);
}

// Wave-level GEMM: C(64 x NT*16) += A(64 x KC*32, LDS bf16) * W^T, W is (N,K) bf16 row-major.
template<int NT, int KC>
__device__ __forceinline__ void mm_tile(const u16* __restrict__ Alds, int strideA,
                                        const u16* __restrict__ W, int Kdim, int n0,
                                        int lrow, int kq, f32x4 (&acc)[4][NT])
{
    #pragma unroll
    for (int kc = 0; kc < KC; ++kc) {
        const int k = kc * 32 + kq;
        s16x8 a[4], b[NT];
        #pragma unroll
        for (int i = 0; i < 4; ++i) a[i] = ldb8(Alds + (i * 16 + lrow) * strideA + k);
        #pragma unroll
        for (int j = 0; j < NT; ++j) b[j] = ldb8(W + (n0 + j * 16 + lrow) * Kdim + k);
        #pragma unroll
        for (int i = 0; i < 4; ++i)
            #pragma unroll
            for (int j = 0; j < NT; ++j)
                acc[i][j] = __builtin_amdgcn_mfma_f32_16x16x32_bf16(a[i], b[j], acc[i][j], 0, 0, 0);
    }
}

// Epilogue: bias (fp32) + optional relu, store bf16 to LDS. C/D map: row=quad*4+r, col=lane&15.
template<int NT>
__device__ __forceinline__ void epilogue_st(u16* __restrict__ out, int strideO,
                                            const float* __restrict__ bias, int n0,
                                            int lrow, int quad, bool relu, f32x4 (&acc)[4][NT])
{
    #pragma unroll
    for (int j = 0; j < NT; ++j) {
        const float bv = bias[n0 + j * 16 + lrow];
        #pragma unroll
        for (int i = 0; i < 4; ++i)
            #pragma unroll
            for (int r = 0; r < 4; ++r) {
                float v = acc[i][j][r] + bv;
                if (relu) v = fmaxf(v, 0.f);
                out[(i * 16 + quad * 4 + r) * strideO + n0 + j * 16 + lrow] = f2b(v);
            }
    }
}

// fp32 -> bf16 (RNE), 4 elements/thread, n divisible by 4.
__global__ void cvt_f32_bf16(const float* __restrict__ src, u16* __restrict__ dst, int n)
{
    const int i = (blockIdx.x * blockDim.x + threadIdx.x) * 4;
    if (i < n) {
        const float4 v = *reinterpret_cast<const float4*>(src + i);
        ushort4 o;
        o.x = f2b(v.x); o.y = f2b(v.y); o.z = f2b(v.z); o.w = f2b(v.w);
        *reinterpret_cast<ushort4*>(dst + i) = o;
    }
}

// ws layout (floats): [0]=recons_sq_sum, [1]=vq_sq_sum, [2..2+KCODES)=|e_k|^2 (from bf16 E)
__global__ void vqvae_norms(const u16* __restrict__ bE, float* __restrict__ ws)
{
    const int c = blockIdx.x * blockDim.x + threadIdx.x;
    if (blockIdx.x == 0 && threadIdx.x < 2) ws[threadIdx.x] = 0.f;
    if (c < KCODES) {
        float s = 0.f;
        const u16* e = bE + c * DDIM;
        for (int i = 0; i < DDIM; ++i) { const float f = b2f(e[i]); s += f * f; }
        ws[2 + c] = s;
    }
}

// Main fused kernel. All weights/codebook bf16 (pre-converted in ws); action & biases fp32.
__global__ __launch_bounds__(256) void ActionVQVAE_49452253446164_kernel(
    const float* __restrict__ action,
    const u16* __restrict__ We1, const float* __restrict__ be1,
    const u16* __restrict__ We2, const float* __restrict__ be2,
    const u16* __restrict__ We3, const float* __restrict__ be3,
    const u16* __restrict__ E,
    const u16* __restrict__ Wd1, const float* __restrict__ bd1,
    const u16* __restrict__ Wd2, const float* __restrict__ bd2,
    const u16* __restrict__ Wh,  const float* __restrict__ bh,
    const float* __restrict__ enorms, float* __restrict__ sums)
{
    // buf cols 0..255: h1 -> h2 -> (q | d1) -> d2 (in-place); cols 128..255 hold enc between stages 3..6.
    __shared__ u16   buf[64 * SA];
    __shared__ float red_val[4][64];
    __shared__ int   red_idx[4][64];
    __shared__ int   qidx[64];
    __shared__ float wsum[8];

    const int tid  = threadIdx.x;
    const int wave = tid >> 6;
    const int lane = tid & 63;
    const int lrow = lane & 15;
    const int quad = lane >> 4;
    const int kq   = quad * 8;
    const int base = blockIdx.x * 64;

    float vq_acc = 0.f, rec_acc = 0.f;

    // ---------- Stage 1: h1 = relu(action @ We1^T + be1) -> buf  (K=16, zero-padded to 32)
    {
        const int n0 = wave * 64;
        f32x4 acc[4][4];
        #pragma unroll
        for (int i = 0; i < 4; ++i)
            #pragma unroll
            for (int j = 0; j < 4; ++j) { f32x4 z = {0.f, 0.f, 0.f, 0.f}; acc[i][j] = z; }
        s16x8 a[4], b[4];
        s16x8 zf = {0, 0, 0, 0, 0, 0, 0, 0};
        #pragma unroll
        for (int i = 0; i < 4; ++i) a[i] = zf;
        #pragma unroll
        for (int j = 0; j < 4; ++j) b[j] = zf;
        if (quad < 2) {
            #pragma unroll
            for (int i = 0; i < 4; ++i) {
                const float* p = action + (base + i * 16 + lrow) * ADIM + kq;
                const float4 v0 = *reinterpret_cast<const float4*>(p);
                const float4 v1 = *reinterpret_cast<const float4*>(p + 4);
                s16x8 f;
                f[0] = (short)f2b(v0.x); f[1] = (short)f2b(v0.y);
                f[2] = (short)f2b(v0.z); f[3] = (short)f2b(v0.w);
                f[4] = (short)f2b(v1.x); f[5] = (short)f2b(v1.y);
                f[6] = (short)f2b(v1.z); f[7] = (short)f2b(v1.w);
                a[i] = f;
            }
            #pragma unroll
            for (int j = 0; j < 4; ++j) b[j] = ldb8(We1 + (n0 + j * 16 + lrow) * ADIM + kq);
        }
        #pragma unroll
        for (int i = 0; i < 4; ++i)
            #pragma unroll
            for (int j = 0; j < 4; ++j)
                acc[i][j] = __builtin_amdgcn_mfma_f32_16x16x32_bf16(a[i], b[j], acc[i][j], 0, 0, 0);
        epilogue_st<4>(buf, SA, be1, n0, lrow, quad, true, acc);
    }
    __syncthreads();

    // ---------- Stage 2: h2 = relu(h1 @ We2^T + be2) -> buf (in place)
    {
        const int n0 = wave * 64;
        f32x4 acc[4][4];
        #pragma unroll
        for (int i = 0; i < 4; ++i)
            #pragma unroll
            for (int j = 0; j < 4; ++j) { f32x4 z = {0.f, 0.f, 0.f, 0.f}; acc[i][j] = z; }
        mm_tile<4, 8>(buf, SA, We2, HDIM, n0, lrow, kq, acc);
        __syncthreads();                       // all waves done reading h1
        epilogue_st<4>(buf, SA, be2, n0, lrow, quad, true, acc);
    }
    __syncthreads();

    // ---------- Stage 3: enc = h2 @ We3^T + be3 -> buf cols 128..255
    {
        const int n0 = wave * 32;
        f32x4 acc[4][2];
        #pragma unroll
        for (int i = 0; i < 4; ++i)
            #pragma unroll
            for (int j = 0; j < 2; ++j) { f32x4 z = {0.f, 0.f, 0.f, 0.f}; acc[i][j] = z; }
        mm_tile<2, 8>(buf, SA, We3, HDIM, n0, lrow, kq, acc);
        __syncthreads();                       // all waves done reading h2
        epilogue_st<2>(buf + 128, SA, be3, n0, lrow, quad, false, acc);
    }
    __syncthreads();

    // ---------- Stage 4: argmin_k of d2 = |e_k|^2 - 2*enc.e_k  (|enc|^2 is row-constant)
    {
        s16x8 afr[4][4];                       // hoisted enc fragments [kc][i]
        #pragma unroll
        for (int kc = 0; kc < 4; ++kc) {
            const int k = kc * 32 + kq;
            #pragma unroll
            for (int i = 0; i < 4; ++i) afr[kc][i] = ldb8(buf + (i * 16 + lrow) * SA + 128 + k);
        }
        float minv[16]; int mini[16];
        #pragma unroll
        for (int s = 0; s < 16; ++s) { minv[s] = 3.4e38f; mini[s] = 0; }

        for (int cb = wave * 512; cb < wave * 512 + 512; cb += 64) {
            f32x4 acc[4][4];
            #pragma unroll
            for (int i = 0; i < 4; ++i)
                #pragma unroll
                for (int j = 0; j < 4; ++j) { f32x4 z = {0.f, 0.f, 0.f, 0.f}; acc[i][j] = z; }
            #pragma unroll
            for (int kc = 0; kc < 4; ++kc) {
                const int k = kc * 32 + kq;
                s16x8 b[4];
                #pragma unroll
                for (int j = 0; j < 4; ++j) b[j] = ldb8(E + (cb + j * 16 + lrow) * DDIM + k);
                #pragma unroll
                for (int i = 0; i < 4; ++i)
                    #pragma unroll
                    for (int j = 0; j < 4; ++j)
                        acc[i][j] = __builtin_amdgcn_mfma_f32_16x16x32_bf16(afr[kc][i], b[j], acc[i][j], 0, 0, 0);
            }
            float en[4];
            #pragma unroll
            for (int j = 0; j < 4; ++j) en[j] = enorms[cb + j * 16 + lrow];
            #pragma unroll
            for (int i = 0; i < 4; ++i)
                #pragma unroll
                for (int j = 0; j < 4; ++j)
                    #pragma unroll
                    for (int r = 0; r < 4; ++r) {
                        const float d2 = en[j] - 2.f * acc[i][j][r];
                        const int s = i * 4 + r;
                        if (d2 < minv[s]) { minv[s] = d2; mini[s] = cb + j * 16 + lrow; }
                    }
        }
        // reduce across the 16 lanes of each quad-group (they hold the 16 candidate cols per row)
        #pragma unroll
        for (int off = 1; off < 16; off <<= 1) {
            #pragma unroll
            for (int s = 0; s < 16; ++s) {
                const float ov = __shfl_xor(minv[s], off, 64);
                const int   oi = __shfl_xor(mini[s], off, 64);
                if (ov < minv[s] || (ov == minv[s] && oi < mini[s])) { minv[s] = ov; mini[s] = oi; }
            }
        }
        if (lrow == 0) {
            #pragma unroll
            for (int i = 0; i < 4; ++i)
                #pragma unroll
                for (int r = 0; r < 4; ++r) {
                    red_val[wave][i * 16 + quad * 4 + r] = minv[i * 4 + r];
                    red_idx[wave][i * 16 + quad * 4 + r] = mini[i * 4 + r];
                }
        }
    }
    __syncthreads();
    if (tid < 64) {
        float bv = red_val[0][tid]; int bi = red_idx[0][tid];
        #pragma unroll
        for (int w = 1; w < 4; ++w) {
            const float v = red_val[w][tid]; const int ii = red_idx[w][tid];
            if (v < bv || (v == bv && ii < bi)) { bv = v; bi = ii; }
        }
        qidx[tid] = bi;
    }
    __syncthreads();

    // ---------- Stage 5: gather q -> buf cols 0..127; accumulate vq = sum (enc - q)^2
    {
        const int row = tid >> 2;
        const int c0  = (tid & 3) * 32;
        const int code = qidx[row];
        #pragma unroll
        for (int c = 0; c < 32; c += 8) {
            #pragma unroll
            for (int t = 0; t < 8; ++t) {
                const u16 qv = E[code * DDIM + c0 + c + t];
                const u16 ev = buf[row * SA + 128 + c0 + c + t];
                buf[row * SA + c0 + c + t] = qv;
                const float d = b2f(ev) - b2f(qv);
                vq_acc += d * d;
            }
        }
    }
    __syncthreads();

    // ---------- Stage 6: d1 = relu(q @ Wd1^T + bd1) -> buf (reads cols 0..127, writes 0..255)
    {
        const int n0 = wave * 64;
        f32x4 acc[4][4];
        #pragma unroll
        for (int i = 0; i < 4; ++i)
            #pragma unroll
            for (int j = 0; j < 4; ++j) { f32x4 z = {0.f, 0.f, 0.f, 0.f}; acc[i][j] = z; }
        mm_tile<4, 4>(buf, SA, Wd1, DDIM, n0, lrow, kq, acc);
        __syncthreads();
        epilogue_st<4>(buf, SA, bd1, n0, lrow, quad, true, acc);
    }
    __syncthreads();

    // ---------- Stage 7: d2 = relu(d1 @ Wd2^T + bd2) -> buf (in place)
    {
        const int n0 = wave * 64;
        f32x4 acc[4][4];
        #pragma unroll
        for (int i = 0; i < 4; ++i)
            #pragma unroll
            for (int j = 0; j < 4; ++j) { f32x4 z = {0.f, 0.f, 0.f, 0.f}; acc[i][j] = z; }
        mm_tile<4, 8>(buf, SA, Wd2, HDIM, n0, lrow, kq, acc);
        __syncthreads();
        epilogue_st<4>(buf, SA, bd2, n0, lrow, quad, true, acc);
    }
    __syncthreads();

    // ---------- Stage 8: recons = tanh(d2 @ Wh^T + bh); accumulate (recons - action)^2 in fp32
    {
        const int m0 = wave * 16;
        f32x4 acc = {0.f, 0.f, 0.f, 0.f};
        #pragma unroll
        for (int kc = 0; kc < 8; ++kc) {
            const int k = kc * 32 + kq;
            s16x8 a = ldb8(buf + (m0 + lrow) * SA + k);
            s16x8 b = ldb8(Wh + lrow * HDIM + k);
            acc = __builtin_amdgcn_mfma_f32_16x16x32_bf16(a, b, acc, 0, 0, 0);
        }
        const float bias = bh[lrow];
        #pragma unroll
        for (int r = 0; r < 4; ++r) {
            const int row = m0 + quad * 4 + r;
            const float v = tanhf(acc[r] + bias);
            const float av = action[(base + row) * ADIM + lrow];
            const float d = v - av;
            rec_acc += d * d;
        }
    }

    // ---------- block reduction + atomics
    #pragma unroll
    for (int off = 1; off < 64; off <<= 1) {
        vq_acc  += __shfl_xor(vq_acc,  off, 64);
        rec_acc += __shfl_xor(rec_acc, off, 64);
    }
    if (lane == 0) { wsum[wave] = rec_acc; wsum[4 + wave] = vq_acc; }
    __syncthreads();
    if (tid == 0) {
        atomicAdd(&sums[0], wsum[0] + wsum[1] + wsum[2] + wsum[3]);
        atomicAdd(&sums[1], wsum[4] + wsum[5] + wsum[6] + wsum[7]);
    }
}

__global__ void vqvae_final(const float* __restrict__ sums, float* __restrict__ out)
{
    if (threadIdx.x == 0 && blockIdx.x == 0) {
        const float recons_loss = sums[0] / (float)(BATCH * ADIM);
        const float vq_loss     = 1.25f * (sums[1] / (float)(BATCH * DDIM));
        out[0] = recons_loss + vq_loss;   // fp32 output, matching the reference dtype
    }
}

extern "C" void kernel_launch(void* const* d_in, const int* in_sizes, int n_in,
                              void* d_out, int out_size, void* d_ws, size_t ws_size,
                              hipStream_t stream)
{
    const float* action = (const float*)d_in[0];
    const float* We1f = (const float*)d_in[1];
    const float* be1  = (const float*)d_in[2];
    const float* We2f = (const float*)d_in[3];
    const float* be2  = (const float*)d_in[4];
    const float* We3f = (const float*)d_in[5];
    const float* be3  = (const float*)d_in[6];
    const float* Ef   = (const float*)d_in[7];
    const float* Wd1f = (const float*)d_in[8];
    const float* bd1  = (const float*)d_in[9];
    const float* Wd2f = (const float*)d_in[10];
    const float* bd2  = (const float*)d_in[11];
    const float* Whf  = (const float*)d_in[12];
    const float* bh   = (const float*)d_in[13];

    float* ws = (float*)d_ws;          // [0..1] sums, [2..2049] enorms
    u16* wb = (u16*)(ws + 2052);       // bf16 area, 16B-aligned (8208 bytes offset)
    u16* bE   = wb;                    // 2048*128 = 262144
    u16* bWe1 = bE   + KCODES * DDIM;  // 4096
    u16* bWe2 = bWe1 + HDIM * ADIM;    // 65536
    u16* bWe3 = bWe2 + HDIM * HDIM;    // 32768
    u16* bWd1 = bWe3 + DDIM * HDIM;    // 32768
    u16* bWd2 = bWd1 + HDIM * DDIM;    // 65536
    u16* bWh  = bWd2 + HDIM * HDIM;    // 4096

    #define CVT(src, dst, n) cvt_f32_bf16<<<((n) / 4 + 255) / 256, 256, 0, stream>>>((src), (dst), (n))
    CVT(Ef,   bE,   KCODES * DDIM);
    CVT(We1f, bWe1, HDIM * ADIM);
    CVT(We2f, bWe2, HDIM * HDIM);
    CVT(We3f, bWe3, DDIM * HDIM);
    CVT(Wd1f, bWd1, HDIM * DDIM);
    CVT(Wd2f, bWd2, HDIM * HDIM);
    CVT(Whf,  bWh,  ADIM * HDIM);
    #undef CVT

    vqvae_norms<<<KCODES / 256, 256, 0, stream>>>(bE, ws);
    ActionVQVAE_49452253446164_kernel<<<BATCH / 64, 256, 0, stream>>>(
        action, bWe1, be1, bWe2, be2, bWe3, be3,
        bE, bWd1, bd1, bWd2, bd2, bWh, bh,
        ws + 2, ws);
    vqvae_final<<<1, 64, 0, stream>>>(ws, (float*)d_out);
}